// Round 8
// baseline (2208.362 us; speedup 1.0000x reference)
//
#include <hip/hip_runtime.h>
#include <hip/hip_bf16.h>

typedef __bf16 bf16x8 __attribute__((ext_vector_type(8)));
typedef float  f32x4  __attribute__((ext_vector_type(4)));

#define NB    32                  // batch
#define NT    256                 // timesteps
#define NF    512                 // input features
#define NH    1024                // hidden
#define NBLK  256                 // grid blocks (1 per CU)
#define NTHR  512                 // threads per block (8 waves)
#define NCTR  64                  // barrier counters (4 blocks each)
#define CTRPAD 32                 // uints per counter (128B padding)
#define HSEQSZ (NB * NH)          // 32768 elems per timestep slab (bf16), layout [u][b]
#define PADK  8
#define LROW  (NH + PADK)         // 1032 elems; row stride 2064B = 129 slots (odd)
#define LROWB (LROW * 2)          // row stride bytes
#define H2SZ  (NB * NT * NH)      // h2 output elems
#define HHOFF H2SZ                // hh base in d_out
#define CCOFF (H2SZ + 2 * NB * NH)// cc base in d_out
#define LSTR  (NB * NH)           // layer stride inside hh/cc
// bank swizzle: rows 8 apart alias the same 16B slot (8*2064 % 128 == 0);
// flipping slot-bit-2 with row-bit-3 makes both stage-writes and mfma-reads 2-way (free).
#define SWZ(row) (((row) & 8) << 3)

__device__ __forceinline__ unsigned short f2bf(float f) {
  __bf16 h = (__bf16)f;
  return __builtin_bit_cast(unsigned short, h);
}

// ---------------- fp32 -> bf16 convert for x; also zeroes barrier counters ----------------
__global__ void cvt_x_kernel(const float* __restrict__ x, unsigned short* __restrict__ xb,
                             unsigned int* __restrict__ counters) {
  if (blockIdx.x == 0) {
    for (int i = threadIdx.x; i < NCTR * CTRPAD; i += 256) counters[i] = 0;
  }
  long i = (long)(blockIdx.x * blockDim.x + threadIdx.x) * 8;
  float4 a = *reinterpret_cast<const float4*>(x + i);
  float4 b = *reinterpret_cast<const float4*>(x + i + 4);
  uint4 o;
  o.x = (unsigned)f2bf(a.x) | ((unsigned)f2bf(a.y) << 16);
  o.y = (unsigned)f2bf(a.z) | ((unsigned)f2bf(a.w) << 16);
  o.z = (unsigned)f2bf(b.x) | ((unsigned)f2bf(b.y) << 16);
  o.w = (unsigned)f2bf(b.z) | ((unsigned)f2bf(b.w) << 16);
  *reinterpret_cast<uint4*>(xb + i) = o;
}

// Load N MFMA B-fragments for this wave into REGISTERS (fp32 global -> bf16).
template<int N>
__device__ __forceinline__ void load_wfrags(const float* __restrict__ W, int K, int kofs,
                                            int grow, int ksub, bf16x8* dst) {
#pragma unroll
  for (int ks = 0; ks < N; ++ks) {
    const float* p = W + (long)grow * K + kofs + ks * 32 + ksub * 8;
    float4 a = *reinterpret_cast<const float4*>(p);
    float4 b = *reinterpret_cast<const float4*>(p + 4);
    bf16x8 fr;
    fr[0]=(__bf16)a.x; fr[1]=(__bf16)a.y; fr[2]=(__bf16)a.z; fr[3]=(__bf16)a.w;
    fr[4]=(__bf16)b.x; fr[5]=(__bf16)b.y; fr[6]=(__bf16)b.z; fr[7]=(__bf16)b.w;
    dst[ks] = fr;
  }
}

// 8 ksteps over GLOBAL memory (xb only): stage 8 loads, then 8 MFMAs, 4 acc chains.
__device__ __forceinline__ void mac8(const unsigned short* __restrict__ ap,
                                     const bf16x8* wr, f32x4* ac) {
  bf16x8 st[8];
#pragma unroll
  for (int j = 0; j < 8; ++j) st[j] = *reinterpret_cast<const bf16x8*>(ap + j * 32);
#pragma unroll
  for (int j = 0; j < 8; ++j)
    ac[j & 3] = __builtin_amdgcn_mfma_f32_16x16x32_bf16(st[j], wr[j], ac[j & 3], 0, 0, 0);
}

__device__ __forceinline__ float sigm(float x) { return 1.f / (1.f + __expf(-x)); }

// Persistent fused 2-layer LSTM. 256 blocks x 512 threads (8 waves), 1 block/CU.
// h buffers [t][unit][batch]: full-line block writes; readers stage the 64KB slab
// into LDS transposed to [b][k] (8x8 register transpose) with XOR bank swizzle.
__global__ __launch_bounds__(NTHR, 2)
void lstm_fused_kernel(const unsigned short* __restrict__ xb,
                       const float* __restrict__ w0w, const float* __restrict__ w0b,
                       const float* __restrict__ u0w, const float* __restrict__ u0b,
                       const float* __restrict__ w1w, const float* __restrict__ w1b,
                       const float* __restrict__ u1w, const float* __restrict__ u1b,
                       float* __restrict__ out,
                       unsigned short* __restrict__ h0seq,
                       unsigned short* __restrict__ h1seq,
                       unsigned int* __restrict__ counters) {
  extern __shared__ char smem[];
  char* h0l = smem;                         // [32][LROW] bf16, swizzled cols   66KB
  char* h1l = smem + NB * LROWB;            // same                              66KB
  float (*gbuf)[NB * 17] = (float (*)[NB * 17])(smem + 2 * NB * LROWB);        // 8.7KB

  const int tid  = threadIdx.x;
  const int blk  = blockIdx.x;
  const int wave = tid >> 6;
  const int lane = tid & 63;
  const int n16  = lane & 15;   // gate-col within slice / A row
  const int ksub = lane >> 4;   // k-subgroup
  const int rt   = wave & 1;    // batch row-tile
  const int m0   = rt * 16 + n16;
  const int grow = (n16 >> 2) * NH + blk * 4 + (n16 & 3);
  // per-thread LDS read base + swizzle mask for A-fragments (row m0)
  const int xm     = SWZ(m0);
  const int rcol0  = ksub * 16;             // byte col of ksub base
  const char* h0r  = h0l + m0 * LROWB;
  const char* h1r  = h1l + m0 * LROWB;

  // -------- one-time: weights into registers --------
  bf16x8 wreg[32];
  if (wave < 2) {
    load_wfrags<16>(w0w, NF, 0,   grow, ksub, wreg);       // x-proj (K=512)
    load_wfrags<16>(u0w, NH, 0,   grow, ksub, wreg + 16);  // h-part, k 0..511
  } else if (wave < 4) {
    load_wfrags<16>(u0w, NH, 512, grow, ksub, wreg);       // h-part, k 512..1023
  } else if (wave < 6) {
    load_wfrags<32>(w1w, NH, 0,   grow, ksub, wreg);       // L1 input-proj
  } else {
    load_wfrags<32>(u1w, NH, 0,   grow, ksub, wreg);       // L1 recurrence
  }

  // -------- per-thread phase-2 state: (u, b) mapping --------
  float bias0 = 0.f, bias1 = 0.f, bias2 = 0.f, bias3 = 0.f;
  int p2_u = 0, p2_b = 0, p2_hu = 0;
  if (tid < 256) {
    int rr = tid & 127;
    p2_u = rr >> 5; p2_b = rr & 31; p2_hu = blk * 4 + p2_u;
    const float* wb = (tid < 128) ? w0b : w1b;
    const float* ub = (tid < 128) ? u0b : u1b;
    bias0 = wb[0 * NH + p2_hu] + ub[0 * NH + p2_hu];
    bias1 = wb[1 * NH + p2_hu] + ub[1 * NH + p2_hu];
    bias2 = wb[2 * NH + p2_hu] + ub[2 * NH + p2_hu];
    bias3 = wb[3 * NH + p2_hu] + ub[3 * NH + p2_hu];
  }
  float c_state = 0.f;

  // cooperative slab stage: global [k][b] (contiguous) -> LDS [b][k] (swizzled)
  auto stage = [&](const unsigned short* __restrict__ src, char* dst) {
    const int k0 = (tid >> 2) * 8;   // 128 k-tiles (elems)
    const int b0 = (tid & 3) * 8;    // 4 b-tiles
    unsigned r[8][4];
#pragma unroll
    for (int j = 0; j < 8; ++j) {
      uint4 v = *reinterpret_cast<const uint4*>(src + (k0 + j) * NB + b0);
      r[j][0] = v.x; r[j][1] = v.y; r[j][2] = v.z; r[j][3] = v.w;
    }
#pragma unroll
    for (int b = 0; b < 8; ++b) {
      uint4 o;
      unsigned w[4];
#pragma unroll
      for (int m = 0; m < 4; ++m) {
        unsigned lo = r[2 * m][b >> 1], hi = r[2 * m + 1][b >> 1];
        w[m] = (b & 1) ? ((lo >> 16) | (hi & 0xffff0000u))
                       : ((lo & 0xffffu) | (hi << 16));
      }
      o.x = w[0]; o.y = w[1]; o.z = w[2]; o.w = w[3];
      const int row = b0 + b;
      *reinterpret_cast<uint4*>(dst + row * LROWB + ((k0 * 2) ^ SWZ(row))) = o;
    }
  };

  // -------- prologue: x-projection for t=0 (w0/w1) --------
  f32x4 xa[4];
#pragma unroll
  for (int r = 0; r < 4; ++r) xa[r] = (f32x4){0.f, 0.f, 0.f, 0.f};
  if (wave < 2) {
    const unsigned short* xp = xb + ((long)m0 * NT + 0) * NF + ksub * 8;
    mac8(xp, wreg, xa); mac8(xp + 256, wreg + 8, xa);
  }

  for (int s = 0; s <= NT; ++s) {
    // ---------------- stage h slabs into LDS ----------------
    if (s >= 1) stage(h0seq + (long)(s - 1) * HSEQSZ, h0l);
    if (s >= 2) stage(h1seq + (long)(s - 2) * HSEQSZ, h1l);
    __syncthreads();

    // ---------------- phase 1: gate GEMM partials (swizzled LDS reads) ----------------
    if (wave < 2) {
      if (s < NT) {
        f32x4 ac[4] = {xa[0], xa[1], xa[2], xa[3]};
        if (s > 0) {
#pragma unroll
          for (int ks = 0; ks < 16; ++ks) {
            bf16x8 af = *reinterpret_cast<const bf16x8*>(h0r + ((ks * 64 + rcol0) ^ xm));
            ac[ks & 3] = __builtin_amdgcn_mfma_f32_16x16x32_bf16(af, wreg[16 + ks], ac[ks & 3], 0, 0, 0);
          }
        }
        f32x4 acc = (ac[0] + ac[1]) + (ac[2] + ac[3]);
#pragma unroll
        for (int r = 0; r < 4; ++r) gbuf[0][(rt * 16 + ksub * 4 + r) * 17 + n16] = acc[r];
      }
    } else if (wave < 4) {
      if (s < NT) {
        f32x4 ac[4];
#pragma unroll
        for (int r = 0; r < 4; ++r) ac[r] = (f32x4){0.f, 0.f, 0.f, 0.f};
        if (s > 0) {
#pragma unroll
          for (int ks = 0; ks < 16; ++ks) {
            bf16x8 af = *reinterpret_cast<const bf16x8*>(h0r + ((1024 + ks * 64 + rcol0) ^ xm));
            ac[ks & 3] = __builtin_amdgcn_mfma_f32_16x16x32_bf16(af, wreg[ks], ac[ks & 3], 0, 0, 0);
          }
        }
        f32x4 acc = (ac[0] + ac[1]) + (ac[2] + ac[3]);
#pragma unroll
        for (int r = 0; r < 4; ++r) gbuf[1][(rt * 16 + ksub * 4 + r) * 17 + n16] = acc[r];
      }
    } else if (wave < 6) {
      if (s >= 1) {
        f32x4 ac[4];
#pragma unroll
        for (int r = 0; r < 4; ++r) ac[r] = (f32x4){0.f, 0.f, 0.f, 0.f};
#pragma unroll
        for (int ks = 0; ks < 32; ++ks) {
          bf16x8 af = *reinterpret_cast<const bf16x8*>(h0r + ((ks * 64 + rcol0) ^ xm));
          ac[ks & 3] = __builtin_amdgcn_mfma_f32_16x16x32_bf16(af, wreg[ks], ac[ks & 3], 0, 0, 0);
        }
        f32x4 acc = (ac[0] + ac[1]) + (ac[2] + ac[3]);
#pragma unroll
        for (int r = 0; r < 4; ++r) gbuf[2][(rt * 16 + ksub * 4 + r) * 17 + n16] = acc[r];
      }
    } else {
      if (s >= 1) {
        f32x4 ac[4];
#pragma unroll
        for (int r = 0; r < 4; ++r) ac[r] = (f32x4){0.f, 0.f, 0.f, 0.f};
        if (s >= 2) {
#pragma unroll
          for (int ks = 0; ks < 32; ++ks) {
            bf16x8 af = *reinterpret_cast<const bf16x8*>(h1r + ((ks * 64 + rcol0) ^ xm));
            ac[ks & 3] = __builtin_amdgcn_mfma_f32_16x16x32_bf16(af, wreg[ks], ac[ks & 3], 0, 0, 0);
          }
        }
        f32x4 acc = (ac[0] + ac[1]) + (ac[2] + ac[3]);
#pragma unroll
        for (int r = 0; r < 4; ++r) gbuf[3][(rt * 16 + ksub * 4 + r) * 17 + n16] = acc[r];
      }
    }
    __syncthreads();

    // ---------------- phase 2: activations + state update ----------------
    if (tid < 128) {
      if (s < NT) {
        int base = p2_b * 17;
        float gi = sigm(gbuf[0][base +  0 + p2_u] + gbuf[1][base +  0 + p2_u] + bias0);
        float gf = sigm(gbuf[0][base +  4 + p2_u] + gbuf[1][base +  4 + p2_u] + bias1);
        float gg = tanhf(gbuf[0][base +  8 + p2_u] + gbuf[1][base +  8 + p2_u] + bias2);
        float go = sigm(gbuf[0][base + 12 + p2_u] + gbuf[1][base + 12 + p2_u] + bias3);
        c_state = gf * c_state + gi * gg;
        float h = go * tanhf(c_state);
        unsigned hu16 = (unsigned)f2bf(h);
        unsigned other = __shfl_down(hu16, 1);
        if ((tid & 1) == 0) {   // pack (b, b+1): contiguous full-line block writes
          unsigned pk = hu16 | (other << 16);
          __hip_atomic_store((unsigned*)(h0seq + (long)s * HSEQSZ + p2_hu * NB + p2_b),
                             pk, __ATOMIC_RELAXED, __HIP_MEMORY_SCOPE_AGENT);
        }
        if (s == NT - 1) {
          out[HHOFF + 0 * LSTR + p2_b * NH + p2_hu] = h;
          out[CCOFF + 0 * LSTR + p2_b * NH + p2_hu] = c_state;
        }
      }
    } else if (tid < 256) {
      if (s >= 1) {
        int t = s - 1;
        int base = p2_b * 17;
        float gi = sigm(gbuf[2][base +  0 + p2_u] + gbuf[3][base +  0 + p2_u] + bias0);
        float gf = sigm(gbuf[2][base +  4 + p2_u] + gbuf[3][base +  4 + p2_u] + bias1);
        float gg = tanhf(gbuf[2][base +  8 + p2_u] + gbuf[3][base +  8 + p2_u] + bias2);
        float go = sigm(gbuf[2][base + 12 + p2_u] + gbuf[3][base + 12 + p2_u] + bias3);
        c_state = gf * c_state + gi * gg;
        float h = go * tanhf(c_state);
        unsigned hu16 = (unsigned)f2bf(h);
        unsigned other = __shfl_down(hu16, 1);
        if ((tid & 1) == 0) {
          unsigned pk = hu16 | (other << 16);
          __hip_atomic_store((unsigned*)(h1seq + (long)t * HSEQSZ + p2_hu * NB + p2_b),
                             pk, __ATOMIC_RELAXED, __HIP_MEMORY_SCOPE_AGENT);
        }
        if (t == NT - 1) {
          out[HHOFF + 1 * LSTR + p2_b * NH + p2_hu] = h;
          out[CCOFF + 1 * LSTR + p2_b * NH + p2_hu] = c_state;
        }
      }
    }

    // ---------------- grid barrier (relaxed; x-proj for s+1 hides under it) ----------------
    {
      if (wave < 4) asm volatile("s_waitcnt vmcnt(0)" ::: "memory");  // drain sc1 h stores
      __syncthreads();
      if (tid == 0)
        __hip_atomic_fetch_add(counters + (blk & (NCTR - 1)) * CTRPAD, 1u,
                               __ATOMIC_RELAXED, __HIP_MEMORY_SCOPE_AGENT);
      if (wave < 2) {   // compute next timestep's x-projection while waiting
#pragma unroll
        for (int r = 0; r < 4; ++r) xa[r] = (f32x4){0.f, 0.f, 0.f, 0.f};
        if (s + 1 < NT) {
          const unsigned short* xp = xb + ((long)m0 * NT + (s + 1)) * NF + ksub * 8;
          mac8(xp, wreg, xa); mac8(xp + 256, wreg + 8, xa);
        }
      }
      if (wave == 7) {  // single-wave poll: lane l watches counter l
        const unsigned target = (unsigned)(NBLK / NCTR) * (unsigned)(s + 1);
        unsigned int* pp = counters + (lane & (NCTR - 1)) * CTRPAD;
        for (;;) {
          unsigned v = __hip_atomic_load(pp, __ATOMIC_RELAXED, __HIP_MEMORY_SCOPE_AGENT);
          if (__all(v >= target)) break;
          __builtin_amdgcn_s_sleep(1);
        }
      }
      __syncthreads();
    }
  }

  // ---------------- epilogue: h2 write (bf16 h1seq [u][b] -> fp32 out [b][t][u]) ----------------
  // Block j owns timestep t=j; 8x8 register transpose per thread, 32B fp32 stores.
  {
    const unsigned short* src = h1seq + (long)blk * HSEQSZ;
    const int k0 = (tid >> 2) * 8;
    const int b0 = (tid & 3) * 8;
    unsigned r[8][4];
#pragma unroll
    for (int j = 0; j < 8; ++j) {
      uint4 v = *reinterpret_cast<const uint4*>(src + (k0 + j) * NB + b0);
      r[j][0] = v.x; r[j][1] = v.y; r[j][2] = v.z; r[j][3] = v.w;
    }
#pragma unroll
    for (int b = 0; b < 8; ++b) {
      float f[8];
#pragma unroll
      for (int j = 0; j < 8; ++j) {
        unsigned u16v = (b & 1) ? (r[j][b >> 1] >> 16) : (r[j][b >> 1] & 0xffffu);
        f[j] = __builtin_bit_cast(float, u16v << 16);
      }
      float* dst = out + ((long)(b0 + b) * NT + blk) * NH + k0;
      float4 lo4 = {f[0], f[1], f[2], f[3]};
      float4 hi4 = {f[4], f[5], f[6], f[7]};
      *reinterpret_cast<float4*>(dst)     = lo4;
      *reinterpret_cast<float4*>(dst + 4) = hi4;
    }
  }
}

extern "C" void kernel_launch(void* const* d_in, const int* in_sizes, int n_in,
                              void* d_out, int out_size, void* d_ws, size_t ws_size,
                              hipStream_t stream) {
  const float* x   = (const float*)d_in[0];
  const float* w0w = (const float*)d_in[1];
  const float* w0b = (const float*)d_in[2];
  const float* u0w = (const float*)d_in[3];
  const float* u0b = (const float*)d_in[4];
  const float* w1w = (const float*)d_in[5];
  const float* w1b = (const float*)d_in[6];
  const float* u1w = (const float*)d_in[7];
  const float* u1b = (const float*)d_in[8];
  float* out = (float*)d_out;

  // ws layout: [counters 8KB][xb bf16 8.4MB][h0seq bf16 16.8MB][h1seq bf16 16.8MB]
  unsigned int*   counters = (unsigned int*)d_ws;
  unsigned short* xb       = (unsigned short*)d_ws + NCTR * CTRPAD * 2;
  unsigned short* h0seq    = xb + (long)NB * NT * NF;
  unsigned short* h1seq    = h0seq + (long)NT * HSEQSZ;

  cvt_x_kernel<<<dim3((NB * NT * NF) / (256 * 8)), dim3(256), 0, stream>>>(x, xb, counters);

  size_t smem = (size_t)(2 * NB * LROWB) + 4 * (NB * 17) * sizeof(float);  // 140800
  (void)hipFuncSetAttribute((const void*)lstm_fused_kernel,
                            hipFuncAttributeMaxDynamicSharedMemorySize, (int)smem);

  void* args[] = {&xb, &w0w, &w0b, &u0w, &u0b, &w1w, &w1b, &u1w, &u1b, &out,
                  &h0seq, &h1seq, &counters};
  (void)hipLaunchCooperativeKernel((const void*)lstm_fused_kernel,
                                   dim3(NBLK), dim3(NTHR), args, (unsigned int)smem, stream);
}